// Round 11
// baseline (432.826 us; speedup 1.0000x reference)
//
#include <hip/hip_runtime.h>
#include <stdint.h>

// positional_spiking_attention — v11: A-resident-LDS, W-streamed-to-registers.
// Spikes {0,1} (exact). Weights w = s1*a1 + s2*a2 (i8 planes); i32 MFMA accum
// exact -> bitwise = v7..v10. Near-threshold columns (|m-0.5|<1e-3) compacted
// + recomputed with the bit-exact serial ascending fp32 chain.
//
// GEMM: block = 32 spike-rows (A tile 16KB in LDS, staged ONCE, one barrier).
// 512 blocks (2/CU). Wave = 16 rows x 256 cols. 6 passes (3 mats x 2 col-
// chunks) x 8 ks; per ks: 1 A ds_read + 16 W global dwordx4 (L2-hot, 2-deep
// reg double-buffer) + 16 MFMA. ZERO barriers in the main loop. W is 2MB ->
// L2-resident; A read once from HBM.
// q/k/v spikes stored PACKED u32 [bi][e] (byte t = spike at time t): one
// dword store per (bi,e), 64B segments; attn reads 4 t-steps per load.
//
// Workspace:
//   0    xsb  u8 first-LIF spikes [bi*4+t][512] (8MB)
//   8M   qs32 / 16M ks32 / 24M vs32  u32-packed [bi][512] (8MB each)
//   32M  sA   u8 attn spikes [bi*4+t][512] (8MB)
//   40M  Wq   4 mats x 2 planes x 512x512 i8 (plane-major flat, 2MB)
//   44M  scl  [mat][2][512] f32 scales
//   48M  list u32 flagged ids (cap 5M) ; 70M cnt

#define T_ 4
#define B_ 4
#define L_ 1024
#define D_ 512
#define BI_ (B_*L_)                 // 4096 (b,l) columns
#define STRIDE4 (B_*L_*D_/4)        // 524288 4-elem groups per t-slice
#define INV_STD 0.9999950000374997f
#define EPS_FLAG 1e-3f
#define LIST_CAP 5000000u

typedef unsigned int   u32;
typedef unsigned char  u8;
typedef int i32x4 __attribute__((ext_vector_type(4)));

static __device__ __forceinline__ float spike_of(float m) {
  return m > 0.5f ? 1.0f : 0.0f;
}

__device__ __forceinline__ void gll16(const void* g, void* l) {
  __builtin_amdgcn_global_load_lds(
      (const __attribute__((address_space(1))) u32*)g,
      (__attribute__((address_space(3))) u32*)l, 16, 0, 0);
}

// ------ weight quantize: w = s1*a1 + s2*a2, plane-major flat ----------------
__global__ __launch_bounds__(256) void k_wsplit(const float* __restrict__ qw,
    const float* __restrict__ kw, const float* __restrict__ vw,
    const float* __restrict__ lw, u8* __restrict__ Wq,
    float* __restrict__ scl, u32* __restrict__ cnt) {
  if (blockIdx.x == 0 && threadIdx.x == 0) *cnt = 0;
  int gid = blockIdx.x * 4 + (threadIdx.x >> 6);   // wave id 0..2047
  int mat = gid >> 9, e = gid & 511;
  int lane = threadIdx.x & 63;
  const float* W = mat == 0 ? qw : mat == 1 ? kw : mat == 2 ? vw : lw;
  const float4* w4 = (const float4*)(W + (size_t)e * 512 + lane * 8);
  float4 wa = w4[0], wb = w4[1];
  float w[8] = {wa.x, wa.y, wa.z, wa.w, wb.x, wb.y, wb.z, wb.w};
  float am = 0.f;
#pragma unroll
  for (int j = 0; j < 8; ++j) am = fmaxf(am, fabsf(w[j]));
#pragma unroll
  for (int off = 1; off < 64; off <<= 1)
    am = fmaxf(am, __shfl_xor(am, off, 64));
  float s1 = am > 0.f ? am * (1.0f / 127.0f) : 1.0f;
  float s2 = s1 * (1.0f / 254.0f);
  float inv1 = 1.0f / s1, inv2 = 1.0f / s2;
  u32 p1lo = 0, p1hi = 0, p2lo = 0, p2hi = 0;
#pragma unroll
  for (int j = 0; j < 8; ++j) {
    float q1 = rintf(w[j] * inv1);
    q1 = fminf(127.f, fmaxf(-127.f, q1));
    float r = w[j] - s1 * q1;
    float q2 = rintf(r * inv2);
    q2 = fminf(127.f, fmaxf(-127.f, q2));
    u32 b1 = (u32)(u8)(signed char)(int)q1;
    u32 b2 = (u32)(u8)(signed char)(int)q2;
    if (j < 4) { p1lo |= b1 << (j * 8); p2lo |= b2 << (j * 8); }
    else       { p1hi |= b1 << ((j - 4) * 8); p2hi |= b2 << ((j - 4) * 8); }
  }
  u8* base = Wq + (size_t)mat * 524288 + (size_t)e * 512 + lane * 8;
  *(uint2*)base            = make_uint2(p1lo, p1hi);   // plane 0
  *(uint2*)(base + 262144) = make_uint2(p2lo, p2hi);   // plane 1
  if (lane == 0) {
    scl[mat * 1024 + e] = s1;
    scl[mat * 1024 + 512 + e] = s2;
  }
}

// ---------------- first LIF: x[t][bi][d] -> xsb[bi*4+t][d] (u8) -------------
__global__ __launch_bounds__(256) void k_lif_first(const float* __restrict__ x,
                                                   u8* __restrict__ xsb) {
  int idx = blockIdx.x * 256 + threadIdx.x;       // bi*128 + d4
  if (idx >= STRIDE4) return;
  const int bi = idx >> 7, d4 = idx & 127;
  const float4* x4 = (const float4*)x;
  uchar4* o4 = (uchar4*)xsb;
  float m[4], s[4];
  float4 v = x4[idx];
  m[0] = v.x; m[1] = v.y; m[2] = v.z; m[3] = v.w;
#pragma unroll
  for (int c = 0; c < 4; ++c) s[c] = spike_of(m[c]);
  o4[(bi * 4 + 0) * 128 + d4] =
      make_uchar4((u8)s[0], (u8)s[1], (u8)s[2], (u8)s[3]);
#pragma unroll
  for (int t = 1; t < T_; ++t) {
    v = x4[idx + t * STRIDE4];
    float xv[4] = {v.x, v.y, v.z, v.w};
#pragma unroll
    for (int c = 0; c < 4; ++c) {
      m[c] = m[c] * 0.25f * (1.0f - s[c]) + xv[c];
      s[c] = spike_of(m[c]);
    }
    o4[(bi * 4 + t) * 128 + d4] =
        make_uchar4((u8)s[0], (u8)s[1], (u8)s[2], (u8)s[3]);
  }
}

// ======= A-resident W-streamed i8 GEMM helpers ==============================
__device__ __forceinline__ void loadw(uint4 (&buf)[8], const u8* wbase,
                                      int pl, int ks) {
#pragma unroll
  for (int cf = 0; cf < 8; ++cf)
    buf[cf] = *(const uint4*)(wbase + (size_t)pl * 262144 + cf * 8192 + ks * 64);
}

template <int PL>
__device__ __forceinline__ void mm8(i32x4 (&acc)[8][2], uint4 aF,
                                    const uint4 (&buf)[8]) {
#pragma unroll
  for (int cf = 0; cf < 8; ++cf)
    acc[cf][PL] = __builtin_amdgcn_mfma_i32_16x16x64_i8(
        __builtin_bit_cast(i32x4, aF), __builtin_bit_cast(i32x4, buf[cf]),
        acc[cf][PL], 0, 0, 0);
}

// Per-pass core: 16 rows (la) x 128 cols, K=512, 2 planes; zero barriers.
__device__ __forceinline__ void pass_core(const u8* aRow, const u8* wbase,
                                          int la, int lg, i32x4 (&acc)[8][2]) {
#pragma unroll
  for (int cf = 0; cf < 8; ++cf) {
    acc[cf][0] = (i32x4){0, 0, 0, 0};
    acc[cf][1] = (i32x4){0, 0, 0, 0};
  }
  uint4 b0[8], b1[8];
  loadw(b0, wbase, 0, 0);
  loadw(b1, wbase, 1, 0);
#pragma unroll
  for (int ks = 0; ks < 8; ++ks) {
    uint4 aF = *(const uint4*)(aRow + ((((ks * 4 + lg) ^ (la & 7)) << 4)));
    mm8<0>(acc, aF, b0);
    if (ks < 7) loadw(b0, wbase, 0, ks + 1);
    mm8<1>(acc, aF, b1);
    if (ks < 7) loadw(b1, wbase, 1, ks + 1);
  }
}

// ------ fused QKV: GEMM + BN + LIF epilogue -> packed u32 spikes ------------
__global__ __launch_bounds__(256) void k_gemm_qkv(const u8* __restrict__ Ab,
    const u8* __restrict__ Wq, const float* __restrict__ scl,
    const float* __restrict__ qb2, const float* __restrict__ qg,
    const float* __restrict__ qbe,
    const float* __restrict__ kb2, const float* __restrict__ kg,
    const float* __restrict__ kbe,
    const float* __restrict__ vb2, const float* __restrict__ vg,
    const float* __restrict__ vbe,
    u32* __restrict__ qs32, u32* __restrict__ ks32, u32* __restrict__ vs32,
    u32* __restrict__ list, u32* __restrict__ cnt) {
  __shared__ __align__(16) u8 smA[16384];
  const int tid = threadIdx.x;
  const int lane = tid & 63, w = tid >> 6;
  const int la = lane & 15, lg = lane >> 4;
  const int row0 = blockIdx.x * 32;               // 512 blocks x 32 rows

  // stage A once (source pre-swizzled; LDS dest linear)
#pragma unroll
  for (int u = 0; u < 4; ++u) {
    int lin = u * 4096 + tid * 16;
    int r = lin >> 9, slot = (lin >> 4) & 31;
    gll16(Ab + (size_t)(row0 + r) * 512 + ((slot ^ (r & 7)) << 4), smA + lin);
  }
  __syncthreads();                                // the only barrier

  const int rsub = (w & 1) * 16;                  // wave's row offset
  const int colh = (w >> 1) * 256;                // wave's column half
  const u8* aRow = smA + (size_t)(rsub + la) * 512;
  const int bi = (row0 >> 2) + (w & 1) * 4 + lg;  // this lane's (b,l) column

  for (int mat = 0; mat < 3; ++mat) {
    const float* Bb = mat == 0 ? qb2 : mat == 1 ? kb2 : vb2;
    const float* Gg = mat == 0 ? qg  : mat == 1 ? kg  : vg;
    const float* Be = mat == 0 ? qbe : mat == 1 ? kbe : vbe;
    u32* S32        = mat == 0 ? qs32 : mat == 1 ? ks32 : vs32;
#pragma unroll
    for (int cb = 0; cb < 2; ++cb) {
      const int colbase = colh + cb * 128;
      const u8* wbase = Wq + (size_t)mat * 524288 +
                        (size_t)(colbase + la) * 512 + lg * 16;
      i32x4 acc[8][2];
      pass_core(aRow, wbase, la, lg, acc);

#pragma unroll
      for (int cf = 0; cf < 8; ++cf) {
        int e = colbase + cf * 16 + la;
        float s1 = scl[mat * 1024 + e];
        float s2 = scl[mat * 1024 + 512 + e];
        float csx = INV_STD * Gg[e];
        float cbx = Bb[e], ctx = Be[e];
        float m = 0.f, sp = 0.f;
        u32 pk = 0;
        int fl = 0;
#pragma unroll
        for (int p = 0; p < 4; ++p) {             // p == t
          float raw = s1 * (float)acc[cf][0][p] + s2 * (float)acc[cf][1][p];
          float pre = (raw + cbx) * csx + ctx;
          if (p == 0) m = pre;
          else m = m * 0.25f * (1.0f - sp) + pre;
          sp = spike_of(m);
          if (fabsf(m - 0.5f) < EPS_FLAG) fl = 1;
          pk |= (u32)(sp != 0.0f) << (p * 8);
        }
        S32[(size_t)bi * 512 + e] = pk;
        if (fl) {
          u32 pos = atomicAdd(cnt, 1u);
          if (pos < LIST_CAP)
            list[pos] = ((u32)mat << 21) | (u32)(bi * 512 + e);
        }
      }
    }
  }
}

// -------- last GEMM + BN -> fp32 out [t][bi][d] -----------------------------
__global__ __launch_bounds__(256) void k_gemm_out(const u8* __restrict__ Ab,
    const u8* __restrict__ Wq, const float* __restrict__ scl,
    const float* __restrict__ bias, const float* __restrict__ gamma,
    const float* __restrict__ beta, float* __restrict__ Y) {
  __shared__ __align__(16) u8 smA[16384];
  const int tid = threadIdx.x;
  const int lane = tid & 63, w = tid >> 6;
  const int la = lane & 15, lg = lane >> 4;
  const int row0 = blockIdx.x * 32;

#pragma unroll
  for (int u = 0; u < 4; ++u) {
    int lin = u * 4096 + tid * 16;
    int r = lin >> 9, slot = (lin >> 4) & 31;
    gll16(Ab + (size_t)(row0 + r) * 512 + ((slot ^ (r & 7)) << 4), smA + lin);
  }
  __syncthreads();

  const int rsub = (w & 1) * 16;
  const int colh = (w >> 1) * 256;
  const u8* aRow = smA + (size_t)(rsub + la) * 512;
  const int bi = (row0 >> 2) + (w & 1) * 4 + lg;

#pragma unroll
  for (int cb = 0; cb < 2; ++cb) {
    const int colbase = colh + cb * 128;
    const u8* wbase = Wq + 3u * 524288 + (size_t)(colbase + la) * 512 + lg * 16;
    i32x4 acc[8][2];
    pass_core(aRow, wbase, la, lg, acc);

#pragma unroll
    for (int cf = 0; cf < 8; ++cf) {
      int e = colbase + cf * 16 + la;
      float s1 = scl[3 * 1024 + e];
      float s2 = scl[3 * 1024 + 512 + e];
      float csx = INV_STD * gamma[e];
      float cbx = bias[e], ctx = beta[e];
#pragma unroll
      for (int p = 0; p < 4; ++p) {
        float raw = s1 * (float)acc[cf][0][p] + s2 * (float)acc[cf][1][p];
        Y[((size_t)p * BI_ + bi) * 512 + e] = (raw + cbx) * csx + ctx;
      }
    }
  }
}

// ------- fixup: quad-per-item, exact serial fp32 chain, shfl-combine --------
__device__ __forceinline__ void consume32_u8(const float4 (&wb)[8],
                                             const uint4 (&ab)[2], float& c) {
#pragma unroll
  for (int u = 0; u < 8; ++u) {           // u = group of 4 consecutive j
    float4 w = wb[u];
    uint4 t = ab[u >> 2];
    u32 word = (u & 3) == 0 ? t.x : (u & 3) == 1 ? t.y
             : (u & 3) == 2 ? t.z : t.w;
    c += (word & 0xFFu)       ? w.x : 0.0f;   // strict ascending-j order
    c += (word & 0xFF00u)     ? w.y : 0.0f;
    c += (word & 0xFF0000u)   ? w.z : 0.0f;
    c += (word >> 24)         ? w.w : 0.0f;
  }
}

__global__ __launch_bounds__(128) void k_fixup_c(const u8* __restrict__ xsb,
    u32* __restrict__ qs32, u32* __restrict__ ks32, u32* __restrict__ vs32,
    const float* __restrict__ qw, const float* __restrict__ qb2,
    const float* __restrict__ qg, const float* __restrict__ qbe,
    const float* __restrict__ kw, const float* __restrict__ kb2,
    const float* __restrict__ kg, const float* __restrict__ kbe,
    const float* __restrict__ vw, const float* __restrict__ vb2,
    const float* __restrict__ vg, const float* __restrict__ vbe,
    const u32* __restrict__ list, const u32* __restrict__ cnt) {
  u32 n = *cnt;
  if (n > LIST_CAP) n = LIST_CAP;
  u32 tot = n * 4;
  for (u32 ii = blockIdx.x * 128 + threadIdx.x; ii < tot;
       ii += gridDim.x * 128) {
    u32 i = ii >> 2;
    int t = (int)(ii & 3);
    u32 e = list[i];
    int tz = (int)(e >> 21);
    int col = (int)(e & 0x1FFFFFu);
    int bi = col >> 9, d = col & 511;
    const float* W  = tz == 0 ? qw  : tz == 1 ? kw  : vw;
    const float* Bb = tz == 0 ? qb2 : tz == 1 ? kb2 : vb2;
    const float* Gg = tz == 0 ? qg  : tz == 1 ? kg  : vg;
    const float* Be = tz == 0 ? qbe : tz == 1 ? kbe : vbe;
    u32* S          = tz == 0 ? qs32 : tz == 1 ? ks32 : vs32;
    const float4* w4 = (const float4*)(W + (size_t)d * 512);            // 128
    const uint4*  R  = (const uint4*)(xsb + ((size_t)bi * 4 + t) * 512); // 32

    float4 wA[8], wB[8];
    uint4 aA[2], aB[2];
#pragma unroll
    for (int u = 0; u < 8; ++u) wA[u] = w4[u];
#pragma unroll
    for (int u = 0; u < 2; ++u) aA[u] = R[u];
    float c = 0.f;
#pragma unroll
    for (int ch = 0; ch < 16; ++ch) {     // 16 chunks x 32 j
      if ((ch & 1) == 0) {
        if (ch + 1 < 16) {
          int wb0 = (ch + 1) * 8, ab0 = (ch + 1) * 2;
#pragma unroll
          for (int u = 0; u < 8; ++u) wB[u] = w4[wb0 + u];
#pragma unroll
          for (int u = 0; u < 2; ++u) aB[u] = R[ab0 + u];
        }
        consume32_u8(wA, aA, c);
      } else {
        if (ch + 1 < 16) {
          int wb0 = (ch + 1) * 8, ab0 = (ch + 1) * 2;
#pragma unroll
          for (int u = 0; u < 8; ++u) wA[u] = w4[wb0 + u];
#pragma unroll
          for (int u = 0; u < 2; ++u) aA[u] = R[ab0 + u];
        }
        consume32_u8(wB, aB, c);
      }
    }
    int lane = threadIdx.x & 63;
    int qb = lane & ~3;
    float cq[4];
    cq[0] = __shfl(c, qb + 0, 64);
    cq[1] = __shfl(c, qb + 1, 64);
    cq[2] = __shfl(c, qb + 2, 64);
    cq[3] = __shfl(c, qb + 3, 64);
    float cs = INV_STD * Gg[d];
    float cb = Bb[d], ct = Be[d];
    float m = 0.f, s = 0.f;
    u8 myb = 0;
#pragma unroll
    for (int t2 = 0; t2 < 4; ++t2) {
      float pre = (cq[t2] + cb) * cs + ct;   // identical to GEMM epilogue form
      if (t2 == 0) m = pre;
      else m = m * 0.25f * (1.0f - s) + pre;
      s = spike_of(m);
      if (t2 == t) myb = (u8)s;
    }
    ((u8*)S)[((size_t)bi * 512 + d) * 4 + t] = myb;   // byte t of packed u32
  }
}

// ---------------- banded positional mixing + attn_lif (packed reads) --------
__global__ __launch_bounds__(256) void k_attn(const u32* __restrict__ qs32,
    const u32* __restrict__ ks32, const u32* __restrict__ vs32,
    const float* __restrict__ pos_bias, u8* __restrict__ sout) {
  int idx = blockIdx.x * 256 + threadIdx.x;     // bi*128 + d4
  if (idx >= STRIDE4) return;
  const int d4 = idx & 127;
  const int bi = idx >> 7;
  const int i = bi & (L_ - 1);
  const int wmax = i < 7 ? i : 7;

  float pbv[8];
  const float* pbrow = pos_bias + (size_t)i * L_ + i;
  for (int w = 0; w <= wmax; ++w) pbv[w] = pbrow[-w];

  const uint4* k4 = (const uint4*)ks32;   // row = 128 uint4 (4 cols x 4 t)
  const uint4* v4 = (const uint4*)vs32;
  const uint4* q4 = (const uint4*)qs32;

  float sum[4][4];                        // [t][c]
#pragma unroll
  for (int t = 0; t < 4; ++t)
#pragma unroll
    for (int c = 0; c < 4; ++c) sum[t][c] = 0.f;

  for (int w = wmax; w >= 0; --w) {       // ascending j = i-w
    uint4 ku = k4[(size_t)(bi - w) * 128 + d4];
    uint4 vu = v4[(size_t)(bi - w) * 128 + d4];
    float pb = pbv[w];
    u32 kw[4] = {ku.x, ku.y, ku.z, ku.w};
    u32 vw[4] = {vu.x, vu.y, vu.z, vu.w};
#pragma unroll
    for (int c = 0; c < 4; ++c)
#pragma unroll
      for (int t = 0; t < 4; ++t)
        if (((kw[c] >> (t * 8)) & 255u) && ((vw[c] >> (t * 8)) & 255u))
          sum[t][c] += pb;
  }
  uint4 qu = q4[(size_t)bi * 128 + d4];
  u32 qw[4] = {qu.x, qu.y, qu.z, qu.w};
  float pre[4][4];
#pragma unroll
  for (int t = 0; t < 4; ++t)
#pragma unroll
    for (int c = 0; c < 4; ++c)
      pre[t][c] = ((qw[c] >> (t * 8)) & 255u) ? sum[t][c] : 0.f;

  uchar4* s4 = (uchar4*)sout;
  float m[4], s[4];
#pragma unroll
  for (int c = 0; c < 4; ++c) { m[c] = pre[0][c]; s[c] = spike_of(m[c]); }
  s4[(bi * 4 + 0) * 128 + d4] =
      make_uchar4((u8)s[0], (u8)s[1], (u8)s[2], (u8)s[3]);
#pragma unroll
  for (int t = 1; t < T_; ++t) {
#pragma unroll
    for (int c = 0; c < 4; ++c) {
      m[c] = m[c] * 0.25f * (1.0f - s[c]) + pre[t][c];
      s[c] = spike_of(m[c]);
    }
    s4[(bi * 4 + t) * 128 + d4] =
        make_uchar4((u8)s[0], (u8)s[1], (u8)s[2], (u8)s[3]);
  }
}

extern "C" void kernel_launch(void* const* d_in, const int* in_sizes, int n_in,
                              void* d_out, int out_size, void* d_ws, size_t ws_size,
                              hipStream_t stream) {
  (void)in_sizes; (void)n_in; (void)out_size; (void)ws_size;
  const float* x        = (const float*)d_in[0];
  const float* pos_bias = (const float*)d_in[1];
  const float* q_w    = (const float*)d_in[2];
  const float* q_b    = (const float*)d_in[3];
  const float* q_g    = (const float*)d_in[4];
  const float* q_beta = (const float*)d_in[5];
  const float* k_w    = (const float*)d_in[6];
  const float* k_b    = (const float*)d_in[7];
  const float* k_g    = (const float*)d_in[8];
  const float* k_beta = (const float*)d_in[9];
  const float* v_w    = (const float*)d_in[10];
  const float* v_b    = (const float*)d_in[11];
  const float* v_g    = (const float*)d_in[12];
  const float* v_beta = (const float*)d_in[13];
  const float* last_w    = (const float*)d_in[14];
  const float* last_b    = (const float*)d_in[15];
  const float* last_g    = (const float*)d_in[16];
  const float* last_beta = (const float*)d_in[17];
  float* out = (float*)d_out;

  char* ws = (char*)d_ws;
  u8*    xsb  = (u8*)(ws + 0);
  u32*   qs32 = (u32*)(ws + 8388608);
  u32*   ks32 = (u32*)(ws + 16777216);
  u32*   vs32 = (u32*)(ws + 25165824);
  u8*    sA   = (u8*)(ws + 33554432);
  u8*    Wq   = (u8*)(ws + 41943040);      // 4 x 524288
  float* scl  = (float*)(ws + 46137344);   // 4 x 1024 f32
  u32*   list = (u32*)(ws + 50331648);     // 20 MB cap
  u32*   cnt  = (u32*)(ws + 73400320);

  k_wsplit<<<512, 256, 0, stream>>>(q_w, k_w, v_w, last_w, Wq, scl, cnt);
  k_lif_first<<<2048, 256, 0, stream>>>(x, xsb);

  k_gemm_qkv<<<512, 256, 0, stream>>>(xsb, Wq, scl,
      q_b, q_g, q_beta, k_b, k_g, k_beta, v_b, v_g, v_beta,
      qs32, ks32, vs32, list, cnt);

  k_fixup_c<<<2048, 128, 0, stream>>>(xsb, qs32, ks32, vs32,
      q_w, q_b, q_g, q_beta, k_w, k_b, k_g, k_beta, v_w, v_b, v_g, v_beta,
      list, cnt);

  k_attn<<<2048, 256, 0, stream>>>(qs32, ks32, vs32, pos_bias, sA);

  k_gemm_out<<<512, 256, 0, stream>>>(sA, Wq, scl,
                                      last_b, last_g, last_beta, out);
}

// Round 12
// 314.787 us; speedup vs baseline: 1.3750x; 1.3750x over previous
//
#include <hip/hip_runtime.h>
#include <stdint.h>

// positional_spiking_attention — v12: deep-pipeline i8 GEMM, A-resident,
// B streamed through 3 rotating LDS buffers with uniform counted vmcnt(8).
// Spikes {0,1} (exact). Weights w = s1*a1 + s2*a2 (i8 planes); i32 MFMA accum
// exact. Near-threshold columns (|m-0.5|<1e-3) compacted + recomputed with
// the bit-exact serial ascending fp32 chain. Packed-u32 spike format (v11).
//
// GEMM: block = 32 rows (A 16KB resident, staged once). 12 segments
// (3 mats x 4 col-tiles) x 8 ks = 96 steps. Per step/wave: 2 A + 4 B
// ds_read_b128 + 8 MFMA; stage B(t+3) after 2nd barrier (4 linear gll16).
// B image pre-arranged by k_wsplit: [mat][ct][ks][pl][lg][col^swz][16B].
// BN prefolded: pre = P1*acc0 + P2*acc1 + P3 (P* from k_wsplit).
//
// Workspace:
//   0    xsb  u8 first-LIF spikes [bi*4+t][512] (8MB)
//   8M   qs32 / 16M ks32 / 24M vs32  u32-packed [bi][512] (8MB each)
//   32M  sA   u8 attn spikes [bi*4+t][512] (8MB)
//   40M  Wq   4 mats step-image i8 (2MB)
//   44M  PQ   [mat][512] float4 {P1,P2,P3,-} (32KB)
//   48M  list u32 flagged ids (cap 5M) ; 70M cnt

#define T_ 4
#define B_ 4
#define L_ 1024
#define D_ 512
#define BI_ (B_*L_)                 // 4096 (b,l) columns
#define STRIDE4 (B_*L_*D_/4)        // 524288 4-elem groups per t-slice
#define INV_STD 0.9999950000374997f
#define EPS_FLAG 1e-3f
#define LIST_CAP 5000000u

typedef unsigned int   u32;
typedef unsigned char  u8;
typedef int i32x4 __attribute__((ext_vector_type(4)));

static __device__ __forceinline__ float spike_of(float m) {
  return m > 0.5f ? 1.0f : 0.0f;
}

__device__ __forceinline__ void gll16(const void* g, void* l) {
  __builtin_amdgcn_global_load_lds(
      (const __attribute__((address_space(1))) u32*)g,
      (__attribute__((address_space(3))) u32*)l, 16, 0, 0);
}

template <int N>
__device__ __forceinline__ void vwait() {
  asm volatile("s_waitcnt vmcnt(%0)" :: "n"(N) : "memory");
}

// ------ weight quantize into per-step LDS image + folded BN params ----------
__global__ __launch_bounds__(256) void k_wsplit(const float* __restrict__ qw,
    const float* __restrict__ kw, const float* __restrict__ vw,
    const float* __restrict__ lw,
    const float* __restrict__ qb, const float* __restrict__ qg,
    const float* __restrict__ qbe,
    const float* __restrict__ kb, const float* __restrict__ kg,
    const float* __restrict__ kbe,
    const float* __restrict__ vb, const float* __restrict__ vg,
    const float* __restrict__ vbe,
    const float* __restrict__ lb, const float* __restrict__ lgam,
    const float* __restrict__ lbe,
    u8* __restrict__ Wq, float4* __restrict__ PQ, u32* __restrict__ cnt) {
  if (blockIdx.x == 0 && threadIdx.x == 0) *cnt = 0;
  int gid = blockIdx.x * 4 + (threadIdx.x >> 6);   // wave id 0..2047
  int mat = gid >> 9, e = gid & 511;
  int lane = threadIdx.x & 63;
  const float* W = mat == 0 ? qw : mat == 1 ? kw : mat == 2 ? vw : lw;
  const float4* w4 = (const float4*)(W + (size_t)e * 512 + lane * 8);
  float4 wa = w4[0], wb = w4[1];
  float w[8] = {wa.x, wa.y, wa.z, wa.w, wb.x, wb.y, wb.z, wb.w};
  float am = 0.f;
#pragma unroll
  for (int j = 0; j < 8; ++j) am = fmaxf(am, fabsf(w[j]));
#pragma unroll
  for (int off = 1; off < 64; off <<= 1)
    am = fmaxf(am, __shfl_xor(am, off, 64));
  float s1 = am > 0.f ? am * (1.0f / 127.0f) : 1.0f;
  float s2 = s1 * (1.0f / 254.0f);
  float inv1 = 1.0f / s1, inv2 = 1.0f / s2;
  u32 p1lo = 0, p1hi = 0, p2lo = 0, p2hi = 0;
#pragma unroll
  for (int j = 0; j < 8; ++j) {
    float q1 = rintf(w[j] * inv1);
    q1 = fminf(127.f, fmaxf(-127.f, q1));
    float r = w[j] - s1 * q1;
    float q2 = rintf(r * inv2);
    q2 = fminf(127.f, fmaxf(-127.f, q2));
    u32 b1 = (u32)(u8)(signed char)(int)q1;
    u32 b2 = (u32)(u8)(signed char)(int)q2;
    if (j < 4) { p1lo |= b1 << (j * 8); p2lo |= b2 << (j * 8); }
    else       { p1hi |= b1 << ((j - 4) * 8); p2hi |= b2 << ((j - 4) * 8); }
  }
  // image: [mat][ct][ks][pl][lg][ (col*16)^(lg<<5) ][16B-half]
  int kstep = lane >> 3, lgq = (lane >> 1) & 3;
  int col = e & 127, ct = e >> 7;
  size_t base = (size_t)mat * 524288 + (size_t)ct * 131072 +
                (size_t)kstep * 16384 + (size_t)lgq * 2048 +
                (size_t)(((col * 16) ^ (lgq << 5)) + (lane & 1) * 8);
  *(uint2*)(Wq + base)        = make_uint2(p1lo, p1hi);   // plane 0
  *(uint2*)(Wq + base + 8192) = make_uint2(p2lo, p2hi);   // plane 1
  if (lane == 0) {
    const float* Bb = mat == 0 ? qb : mat == 1 ? kb : mat == 2 ? vb : lb;
    const float* Gg = mat == 0 ? qg : mat == 1 ? kg : mat == 2 ? vg : lgam;
    const float* Be = mat == 0 ? qbe : mat == 1 ? kbe : mat == 2 ? vbe : lbe;
    float cs = INV_STD * Gg[e];
    PQ[mat * 512 + e] = make_float4(s1 * cs, s2 * cs, Bb[e] * cs + Be[e], 0.f);
  }
}

// ---------------- first LIF: x[t][bi][d] -> xsb[bi*4+t][d] (u8) -------------
__global__ __launch_bounds__(256) void k_lif_first(const float* __restrict__ x,
                                                   u8* __restrict__ xsb) {
  int idx = blockIdx.x * 256 + threadIdx.x;       // bi*128 + d4
  if (idx >= STRIDE4) return;
  const int bi = idx >> 7, d4 = idx & 127;
  const float4* x4 = (const float4*)x;
  uchar4* o4 = (uchar4*)xsb;
  float m[4], s[4];
  float4 v = x4[idx];
  m[0] = v.x; m[1] = v.y; m[2] = v.z; m[3] = v.w;
#pragma unroll
  for (int c = 0; c < 4; ++c) s[c] = spike_of(m[c]);
  o4[(bi * 4 + 0) * 128 + d4] =
      make_uchar4((u8)s[0], (u8)s[1], (u8)s[2], (u8)s[3]);
#pragma unroll
  for (int t = 1; t < T_; ++t) {
    v = x4[idx + t * STRIDE4];
    float xv[4] = {v.x, v.y, v.z, v.w};
#pragma unroll
    for (int c = 0; c < 4; ++c) {
      m[c] = m[c] * 0.25f * (1.0f - s[c]) + xv[c];
      s[c] = spike_of(m[c]);
    }
    o4[(bi * 4 + t) * 128 + d4] =
        make_uchar4((u8)s[0], (u8)s[1], (u8)s[2], (u8)s[3]);
  }
}

// ======= deep-pipeline GEMM body (shared by qkv and out via NSEG) ===========
// Stages A once; runs NSEG*8 steps; calls EPI(seg, acc) per segment.
struct GemmCtx {
  const u8* Ab; const u8* Wbase;   // Wbase = Wq + first-mat offset
  int row0, tid;
  u8 *smA, *smB;
};

__device__ __forceinline__ void gemm_prologue(const GemmCtx& c) {
#pragma unroll
  for (int u = 0; u < 4; ++u) {
    int lin = u * 4096 + c.tid * 16;
    int r = lin >> 9, slot = (lin >> 4) & 31;
    int gs = (slot & ~7) | ((slot ^ r) & 7);
    gll16(c.Ab + (size_t)(c.row0 + r) * 512 + gs * 16, c.smA + lin);
  }
#pragma unroll
  for (int t = 0; t < 3; ++t)
#pragma unroll
    for (int u = 0; u < 4; ++u) {
      int lin = u * 4096 + c.tid * 16;
      gll16(c.Wbase + (size_t)t * 16384 + lin, c.smB + t * 16384 + lin);
    }
}

// one K-step: consume buf t%3, stage step min(t+3,tmax) into same buf slot
__device__ __forceinline__ void gemm_step(const GemmCtx& c, int t, int ks,
                                          int tmax, int la, int lg, int wv,
                                          i32x4 (&acc)[2][2][2]) {
  vwait<8>();
  __builtin_amdgcn_s_barrier();
  const u8* bb = c.smB + (t % 3) * 16384;
  uint4 aF[2], bF[2][2];
#pragma unroll
  for (int s = 0; s < 2; ++s) {
    int kc = ks * 4 + lg;
    int phys = (kc & ~7) | ((kc ^ la) & 7);
    aF[s] = *(const uint4*)(c.smA + (s * 16 + la) * 512 + phys * 16);
  }
#pragma unroll
  for (int cf = 0; cf < 2; ++cf)
#pragma unroll
    for (int pl = 0; pl < 2; ++pl)
      bF[cf][pl] = *(const uint4*)(bb + pl * 8192 + lg * 2048 +
                    ((((wv * 32 + cf * 16 + la) * 16)) ^ (lg << 5)));
#pragma unroll
  for (int s = 0; s < 2; ++s)
#pragma unroll
    for (int cf = 0; cf < 2; ++cf)
#pragma unroll
      for (int pl = 0; pl < 2; ++pl)
        acc[s][cf][pl] = __builtin_amdgcn_mfma_i32_16x16x64_i8(
            __builtin_bit_cast(i32x4, aF[s]),
            __builtin_bit_cast(i32x4, bF[cf][pl]), acc[s][cf][pl], 0, 0, 0);
  __builtin_amdgcn_s_barrier();
  int st = t + 3 > tmax ? tmax : t + 3;
  const u8* src = c.Wbase + (size_t)(st >> 3) * 131072 +
                  (size_t)(st & 7) * 16384;
  u8* dst = c.smB + (t % 3) * 16384;
#pragma unroll
  for (int u = 0; u < 4; ++u) {
    int lin = u * 4096 + c.tid * 16;
    gll16(src + lin, dst + lin);
  }
}

// ------ fused QKV: 12-segment pipeline + BN + LIF -> packed u32 spikes ------
__global__ __launch_bounds__(256) void k_gemm_qkv(const u8* __restrict__ Ab,
    const u8* __restrict__ Wq, const float4* __restrict__ PQ,
    u32* __restrict__ qs32, u32* __restrict__ ks32, u32* __restrict__ vs32,
    u32* __restrict__ list, u32* __restrict__ cnt) {
  __shared__ __align__(16) u8 smA[16384];
  __shared__ __align__(16) u8 smB[49152];
  const int tid = threadIdx.x;
  const int lane = tid & 63, wv = tid >> 6;
  const int la = lane & 15, lg = lane >> 4;
  const int row0 = blockIdx.x * 32;

  GemmCtx c{Ab, Wq, row0, tid, smA, smB};
  gemm_prologue(c);

  i32x4 acc[2][2][2];
#pragma unroll
  for (int s = 0; s < 2; ++s)
#pragma unroll
    for (int cf = 0; cf < 2; ++cf)
#pragma unroll
      for (int pl = 0; pl < 2; ++pl) acc[s][cf][pl] = (i32x4){0, 0, 0, 0};

  const int biB = (row0 >> 2) + lg;

  for (int seg = 0; seg < 12; ++seg) {
    const int mat = seg >> 2, ct = seg & 3;
#pragma unroll
    for (int ks = 0; ks < 8; ++ks)
      gemm_step(c, seg * 8 + ks, ks, 95, la, lg, wv, acc);

    u32* S32 = mat == 0 ? qs32 : mat == 1 ? ks32 : vs32;
#pragma unroll
    for (int cf = 0; cf < 2; ++cf) {
      int e = ct * 128 + wv * 32 + cf * 16 + la;
      float4 pq = PQ[mat * 512 + e];
#pragma unroll
      for (int s = 0; s < 2; ++s) {
        int bi = biB + s * 4;
        float m = 0.f, sp = 0.f;
        u32 pk = 0;
        int fl = 0;
#pragma unroll
        for (int p = 0; p < 4; ++p) {          // p == t
          float pre = pq.x * (float)acc[s][cf][0][p] +
                      pq.y * (float)acc[s][cf][1][p] + pq.z;
          if (p == 0) m = pre;
          else m = m * 0.25f * (1.0f - sp) + pre;
          sp = spike_of(m);
          if (fabsf(m - 0.5f) < EPS_FLAG) fl = 1;
          pk |= (u32)(sp != 0.0f) << (p * 8);
        }
        S32[(size_t)bi * 512 + e] = pk;
        if (fl) {
          u32 pos = atomicAdd(cnt, 1u);
          if (pos < LIST_CAP)
            list[pos] = ((u32)mat << 21) | (u32)(bi * 512 + e);
        }
        acc[s][cf][0] = (i32x4){0, 0, 0, 0};
        acc[s][cf][1] = (i32x4){0, 0, 0, 0};
      }
    }
  }
}

// -------- last GEMM (mat 3): 4-segment pipeline -> fp32 out [t][bi][d] ------
__global__ __launch_bounds__(256) void k_gemm_out(const u8* __restrict__ Ab,
    const u8* __restrict__ Wq, const float4* __restrict__ PQ,
    float* __restrict__ Y) {
  __shared__ __align__(16) u8 smA[16384];
  __shared__ __align__(16) u8 smB[49152];
  const int tid = threadIdx.x;
  const int lane = tid & 63, wv = tid >> 6;
  const int la = lane & 15, lg = lane >> 4;
  const int row0 = blockIdx.x * 32;

  GemmCtx c{Ab, Wq + 3u * 524288, row0, tid, smA, smB};
  gemm_prologue(c);

  i32x4 acc[2][2][2];
#pragma unroll
  for (int s = 0; s < 2; ++s)
#pragma unroll
    for (int cf = 0; cf < 2; ++cf)
#pragma unroll
      for (int pl = 0; pl < 2; ++pl) acc[s][cf][pl] = (i32x4){0, 0, 0, 0};

  const int biB = (row0 >> 2) + lg;

  for (int seg = 0; seg < 4; ++seg) {
    const int ct = seg;
#pragma unroll
    for (int ks = 0; ks < 8; ++ks)
      gemm_step(c, seg * 8 + ks, ks, 31, la, lg, wv, acc);

#pragma unroll
    for (int cf = 0; cf < 2; ++cf) {
      int e = ct * 128 + wv * 32 + cf * 16 + la;
      float4 pq = PQ[3 * 512 + e];
#pragma unroll
      for (int s = 0; s < 2; ++s) {
        int bi = biB + s * 4;
#pragma unroll
        for (int p = 0; p < 4; ++p) {
          float pre = pq.x * (float)acc[s][cf][0][p] +
                      pq.y * (float)acc[s][cf][1][p] + pq.z;
          Y[((size_t)p * BI_ + bi) * 512 + e] = pre;
        }
        acc[s][cf][0] = (i32x4){0, 0, 0, 0};
        acc[s][cf][1] = (i32x4){0, 0, 0, 0};
      }
    }
  }
}

// ------- fixup: quad-per-item, exact serial fp32 chain, shfl-combine --------
__device__ __forceinline__ void consume32_u8(const float4 (&wb)[8],
                                             const uint4 (&ab)[2], float& c) {
#pragma unroll
  for (int u = 0; u < 8; ++u) {           // u = group of 4 consecutive j
    float4 w = wb[u];
    uint4 t = ab[u >> 2];
    u32 word = (u & 3) == 0 ? t.x : (u & 3) == 1 ? t.y
             : (u & 3) == 2 ? t.z : t.w;
    c += (word & 0xFFu)       ? w.x : 0.0f;   // strict ascending-j order
    c += (word & 0xFF00u)     ? w.y : 0.0f;
    c += (word & 0xFF0000u)   ? w.z : 0.0f;
    c += (word >> 24)         ? w.w : 0.0f;
  }
}

__global__ __launch_bounds__(128) void k_fixup_c(const u8* __restrict__ xsb,
    u32* __restrict__ qs32, u32* __restrict__ ks32, u32* __restrict__ vs32,
    const float* __restrict__ qw, const float* __restrict__ qb2,
    const float* __restrict__ qg, const float* __restrict__ qbe,
    const float* __restrict__ kw, const float* __restrict__ kb2,
    const float* __restrict__ kg, const float* __restrict__ kbe,
    const float* __restrict__ vw, const float* __restrict__ vb2,
    const float* __restrict__ vg, const float* __restrict__ vbe,
    const u32* __restrict__ list, const u32* __restrict__ cnt) {
  u32 n = *cnt;
  if (n > LIST_CAP) n = LIST_CAP;
  u32 tot = n * 4;
  for (u32 ii = blockIdx.x * 128 + threadIdx.x; ii < tot;
       ii += gridDim.x * 128) {
    u32 i = ii >> 2;
    int t = (int)(ii & 3);
    u32 e = list[i];
    int tz = (int)(e >> 21);
    int col = (int)(e & 0x1FFFFFu);
    int bi = col >> 9, d = col & 511;
    const float* W  = tz == 0 ? qw  : tz == 1 ? kw  : vw;
    const float* Bb = tz == 0 ? qb2 : tz == 1 ? kb2 : vb2;
    const float* Gg = tz == 0 ? qg  : tz == 1 ? kg  : vg;
    const float* Be = tz == 0 ? qbe : tz == 1 ? kbe : vbe;
    u32* S          = tz == 0 ? qs32 : tz == 1 ? ks32 : vs32;
    const float4* w4 = (const float4*)(W + (size_t)d * 512);            // 128
    const uint4*  R  = (const uint4*)(xsb + ((size_t)bi * 4 + t) * 512); // 32

    float4 wA[8], wB[8];
    uint4 aA[2], aB[2];
#pragma unroll
    for (int u = 0; u < 8; ++u) wA[u] = w4[u];
#pragma unroll
    for (int u = 0; u < 2; ++u) aA[u] = R[u];
    float c = 0.f;
#pragma unroll
    for (int ch = 0; ch < 16; ++ch) {     // 16 chunks x 32 j
      if ((ch & 1) == 0) {
        if (ch + 1 < 16) {
          int wb0 = (ch + 1) * 8, ab0 = (ch + 1) * 2;
#pragma unroll
          for (int u = 0; u < 8; ++u) wB[u] = w4[wb0 + u];
#pragma unroll
          for (int u = 0; u < 2; ++u) aB[u] = R[ab0 + u];
        }
        consume32_u8(wA, aA, c);
      } else {
        if (ch + 1 < 16) {
          int wb0 = (ch + 1) * 8, ab0 = (ch + 1) * 2;
#pragma unroll
          for (int u = 0; u < 8; ++u) wA[u] = w4[wb0 + u];
#pragma unroll
          for (int u = 0; u < 2; ++u) aA[u] = R[ab0 + u];
        }
        consume32_u8(wB, aB, c);
      }
    }
    int lane = threadIdx.x & 63;
    int qb = lane & ~3;
    float cq[4];
    cq[0] = __shfl(c, qb + 0, 64);
    cq[1] = __shfl(c, qb + 1, 64);
    cq[2] = __shfl(c, qb + 2, 64);
    cq[3] = __shfl(c, qb + 3, 64);
    float cs = INV_STD * Gg[d];
    float cb = Bb[d], ct = Be[d];
    float m = 0.f, s = 0.f;
    u8 myb = 0;
#pragma unroll
    for (int t2 = 0; t2 < 4; ++t2) {
      float pre = (cq[t2] + cb) * cs + ct;   // exact serial chain
      if (t2 == 0) m = pre;
      else m = m * 0.25f * (1.0f - s) + pre;
      s = spike_of(m);
      if (t2 == t) myb = (u8)s;
    }
    ((u8*)S)[((size_t)bi * 512 + d) * 4 + t] = myb;   // byte t of packed u32
  }
}

// ---------------- banded positional mixing + attn_lif (packed reads) --------
__global__ __launch_bounds__(256) void k_attn(const u32* __restrict__ qs32,
    const u32* __restrict__ ks32, const u32* __restrict__ vs32,
    const float* __restrict__ pos_bias, u8* __restrict__ sout) {
  int idx = blockIdx.x * 256 + threadIdx.x;     // bi*128 + d4
  if (idx >= STRIDE4) return;
  const int d4 = idx & 127;
  const int bi = idx >> 7;
  const int i = bi & (L_ - 1);
  const int wmax = i < 7 ? i : 7;

  float pbv[8];
  const float* pbrow = pos_bias + (size_t)i * L_ + i;
  for (int w = 0; w <= wmax; ++w) pbv[w] = pbrow[-w];

  const uint4* k4 = (const uint4*)ks32;   // row = 128 uint4 (4 cols x 4 t)
  const uint4* v4 = (const uint4*)vs32;
  const uint4* q4 = (const uint4*)qs32;

  float sum[4][4];                        // [t][c]
#pragma unroll
  for (int t = 0; t < 4; ++t)
#pragma unroll
    for (int c = 0; c < 4; ++c) sum[t][c] = 0.f;

  for (int w = wmax; w >= 0; --w) {       // ascending j = i-w
    uint4 ku = k4[(size_t)(bi - w) * 128 + d4];
    uint4 vu = v4[(size_t)(bi - w) * 128 + d4];
    float pb = pbv[w];
    u32 kw[4] = {ku.x, ku.y, ku.z, ku.w};
    u32 vw[4] = {vu.x, vu.y, vu.z, vu.w};
#pragma unroll
    for (int c = 0; c < 4; ++c)
#pragma unroll
      for (int t = 0; t < 4; ++t)
        if (((kw[c] >> (t * 8)) & 255u) && ((vw[c] >> (t * 8)) & 255u))
          sum[t][c] += pb;
  }
  uint4 qu = q4[(size_t)bi * 128 + d4];
  u32 qw[4] = {qu.x, qu.y, qu.z, qu.w};
  float pre[4][4];
#pragma unroll
  for (int t = 0; t < 4; ++t)
#pragma unroll
    for (int c = 0; c < 4; ++c)
      pre[t][c] = ((qw[c] >> (t * 8)) & 255u) ? sum[t][c] : 0.f;

  uchar4* s4 = (uchar4*)sout;
  float m[4], s[4];
#pragma unroll
  for (int c = 0; c < 4; ++c) { m[c] = pre[0][c]; s[c] = spike_of(m[c]); }
  s4[(bi * 4 + 0) * 128 + d4] =
      make_uchar4((u8)s[0], (u8)s[1], (u8)s[2], (u8)s[3]);
#pragma unroll
  for (int t = 1; t < T_; ++t) {
#pragma unroll
    for (int c = 0; c < 4; ++c) {
      m[c] = m[c] * 0.25f * (1.0f - s[c]) + pre[t][c];
      s[c] = spike_of(m[c]);
    }
    s4[(bi * 4 + t) * 128 + d4] =
        make_uchar4((u8)s[0], (u8)s[1], (u8)s[2], (u8)s[3]);
  }
}

extern "C" void kernel_launch(void* const* d_in, const int* in_sizes, int n_in,
                              void* d_out, int out_size, void* d_ws, size_t ws_size,
                              hipStream_t stream) {
  (void)in_sizes; (void)n_in; (void)out_size; (void)ws_size;
  const float* x        = (const float*)d_in[0];
  const float* pos_bias = (const float*)d_in[1];
  const float* q_w    = (const float*)d_in[2];
  const float* q_b    = (const float*)d_in[3];
  const float* q_g    = (const float*)d_in[4];
  const float* q_beta = (const float*)d_in[5];
  const float* k_w    = (const float*)d_in[6];
  const float* k_b    = (const float*)d_in[7];
  const float* k_g    = (const float*)d_in[8];
  const float* k_beta = (const float*)d_in[9];
  const float* v_w    = (const float*)d_in[10];
  const float* v_b    = (const float*)d_in[11];
  const float* v_g    = (const float*)d_in[12];
  const float* v_beta = (const float*)d_in[13];
  const float* last_w    = (const float*)d_in[14];
  const float* last_b    = (const float*)d_in[15];
  const float* last_g    = (const float*)d_in[16];
  const float* last_beta = (const float*)d_in[17];
  float* out = (float*)d_out;

  char* ws = (char*)d_ws;
  u8*    xsb  = (u8*)(ws + 0);
  u32*   qs32 = (u32*)(ws + 8388608);
  u32*   ks32 = (u32*)(ws + 16777216);
  u32*   vs32 = (u32*)(ws + 25165824);
  u8*    sA   = (u8*)(ws + 33554432);
  u8*    Wq   = (u8*)(ws + 41943040);       // 2MB step-image
  float4* PQ  = (float4*)(ws + 46137344);   // 32KB
  u32*   list = (u32*)(ws + 50331648);      // 20 MB cap
  u32*   cnt  = (u32*)(ws + 73400320);

  k_wsplit<<<512, 256, 0, stream>>>(q_w, k_w, v_w, last_w,
      q_b, q_g, q_beta, k_b, k_g, k_beta, v_b, v_g, v_beta,
      last_b, last_g, last_beta, Wq, PQ, cnt);
  k_lif_first<<<2048, 256, 0, stream>>>(x, xsb);

  k_gemm_qkv<<<512, 256, 0, stream>>>(xsb, Wq, PQ,
      qs32, ks32, vs32, list, cnt);

  k_fixup_c<<<2048, 128, 0, stream>>>(xsb, qs32, ks32, vs32,
      q_w, q_b, q_g, q_beta, k_w, k_b, k_g, k_beta, v_w, v_b, v_g, v_beta,
      list, cnt);

  k_attn<<<2048, 256, 0, stream>>>(qs32, ks32, vs32, pos_bias, sA);

  k_gemm_out<<<512, 256, 0, stream>>>(sA, Wq, PQ, out);
}